// Round 4
// baseline (538.000 us; speedup 1.0000x reference)
//
#include <hip/hip_runtime.h>
#include <stdint.h>

// LSTM cell, fp32 I/O: z = x@Wx + h@Wh + bx + bh (M=32768, N=2048, K=1024)
// fused with gate activations and C/h update. bf16 MFMA, fp32 accumulate.
// R8: kill the xh pre-pass. Residual ledger (R0-R3) shows fixed harness cost
//     ~180us + conv/pack ~50us; conv rewrite didn't move it -> fuse the
//     fp32->bf16 cast INTO the GEMM A-staging (reg-stage + ds_write, next
//     K-step's fp32 loads issued early so latency hides under MFMA).
//     Workspace shrinks 68MB -> 4MB (Wt only). B stays global_load_lds.
//     x+h (128MB) L3-resident; XCD-bijective swizzle keeps A-panel L2 reuse;
//     NT epilogue stores preserve L3 for x/h.

#define BROWS 32768
#define DH 512
#define KTOT 1024   // D_IN + D_H
#define BM 128
#define BK 64

typedef __attribute__((ext_vector_type(8))) __bf16 bf16x8;
typedef __attribute__((ext_vector_type(4))) float f32x4;
typedef __attribute__((address_space(1))) void gvoid;
typedef __attribute__((address_space(3))) void lvoid;

__device__ __forceinline__ void gl_lds16(const void* g, void* l) {
  __builtin_amdgcn_global_load_lds((gvoid*)g, (lvoid*)l, 16, 0, 0);
}

__device__ __forceinline__ float sigf(float v)  { return 1.0f / (1.0f + __expf(-v)); }
__device__ __forceinline__ float tanhf_(float v){ return 1.0f - 2.0f / (1.0f + __expf(2.0f * v)); }

// ---- pack: Wt[(jb*128+r)*1024+k], r = (hl>>4)*64 + g*16 + (hl&15),
//      n = g*512 + jb*32 + hl. Coalesced via LDS transpose tile. ----
__global__ void pack_w(const float* __restrict__ Wx, const float* __restrict__ Wh,
                       __bf16* __restrict__ Wt) {
  __shared__ __bf16 T[128][72];                 // +8 pad
  const int jb = blockIdx.y;
  const int k0 = blockIdx.x * 64;
  const float* Wsrc = (k0 < DH) ? (Wx + (size_t)k0 * 4 * DH)
                                : (Wh + (size_t)(k0 - DH) * 4 * DH);
  const int t = threadIdx.x;
  const int s = t & 31, kr0 = t >> 5;           // 32 seg-threads x 8 k-rows
  const int g = s >> 3, q = s & 7;
  const int r0 = (q >> 2) * 64 + g * 16 + (q & 3) * 4;
  #pragma unroll
  for (int it = 0; it < 8; ++it) {
    int kr = it * 8 + kr0;
    float4 f = *(const float4*)(Wsrc + (size_t)kr * 4 * DH + g * DH + jb * 32 + q * 4);
    T[r0 + 0][kr] = (__bf16)f.x;
    T[r0 + 1][kr] = (__bf16)f.y;
    T[r0 + 2][kr] = (__bf16)f.z;
    T[r0 + 3][kr] = (__bf16)f.w;
  }
  __syncthreads();
  #pragma unroll
  for (int it = 0; it < 4; ++it) {
    int lin = it * 256 + t;                     // 0..1023
    int r = lin >> 3, k8 = lin & 7;
    bf16x8 v;
    #pragma unroll
    for (int j = 0; j < 8; ++j) v[j] = T[r][k8 * 8 + j];
    *(bf16x8*)(Wt + (size_t)(jb * 128 + r) * KTOT + k0 + k8 * 8) = v;
  }
}

// ---- fused GEMM: m97 structure, A = fp32 x/h reg-staged with early-issued
//      prefetch + in-kernel bf16 cast; B = packed bf16 via global_load_lds.
//      Both LDS tiles XOR-chunk-swizzled -> conflict-free ds_read_b128. ----
__global__ __launch_bounds__(256, 3) void lstm_fused(
    const float* __restrict__ x, const float* __restrict__ h,
    const __bf16* __restrict__ Wt, const float* __restrict__ bx,
    const float* __restrict__ bh, const float* __restrict__ Cin,
    float* __restrict__ out) {
  __shared__ __attribute__((aligned(16))) __bf16 As[BM * BK];
  __shared__ __attribute__((aligned(16))) __bf16 Bs[BM * BK];

  const int tid  = threadIdx.x;
  const int lane = tid & 63;
  const int wave = tid >> 6;
  const int wm = wave >> 1, wn = wave & 1;

  // T1: bijective XCD swizzle (4096 wgs = 8 XCDs x 512). jb varies fastest
  // within an XCD's run so the 16 blocks sharing one A-panel hit its L2.
  const int wgid = blockIdx.y * 16 + blockIdx.x;
  const int lin  = (wgid & 7) * 512 + (wgid >> 3);
  const int jb   = lin & 15;
  const int row0 = (lin >> 4) * BM;

  const __bf16* Bt = Wt + (size_t)jb * 128 * KTOT;
  const float*  Ax = x + (size_t)row0 * DH;
  const float*  Ah = h + (size_t)row0 * DH;

  // per-thread A staging geometry: pos (r,c8) holds global chunk c8^(r&7)
  int sr_[4], sc_[4];
  #pragma unroll
  for (int it = 0; it < 4; ++it) {
    int l2 = it * 256 + tid;
    sr_[it] = l2 >> 3;
    sc_[it] = (l2 & 7) ^ (sr_[it] & 7);
  }

  // A prefetch registers (fp32), one K-step ahead
  float4 pf[4][2];
  {
    const float* base = Ax;                      // k0 = 0 < DH
    #pragma unroll
    for (int it = 0; it < 4; ++it) {
      const float* s = base + (size_t)sr_[it] * DH + sc_[it] * 8;
      pf[it][0] = *(const float4*)s;
      pf[it][1] = *(const float4*)(s + 4);
    }
  }

  // bias + C prefetch (latency hidden behind K-loop)
  const int hd = jb * 32 + wn * 16 + (lane & 15);
  float bias[4], cpv[4][4];
  #pragma unroll
  for (int g = 0; g < 4; ++g) bias[g] = bx[g * DH + hd] + bh[g * DH + hd];
  #pragma unroll
  for (int cm = 0; cm < 4; ++cm)
    #pragma unroll
    for (int i2 = 0; i2 < 4; ++i2)
      cpv[cm][i2] = Cin[(size_t)(row0 + wm * 64 + cm * 16 + (lane >> 4) * 4 + i2) * DH + hd];

  f32x4 acc[4][4];
  #pragma unroll
  for (int a_ = 0; a_ < 4; ++a_)
    #pragma unroll
    for (int b_ = 0; b_ < 4; ++b_) acc[a_][b_] = (f32x4)0.0f;

  for (int k0 = 0; k0 < KTOT; k0 += BK) {
    // stage A: cvt prefetched fp32 -> bf16x8, ds_write_b128 (contiguous,
    // 2-way bank alias = free)
    #pragma unroll
    for (int it = 0; it < 4; ++it) {
      bf16x8 v;
      v[0] = (__bf16)pf[it][0].x; v[1] = (__bf16)pf[it][0].y;
      v[2] = (__bf16)pf[it][0].z; v[3] = (__bf16)pf[it][0].w;
      v[4] = (__bf16)pf[it][1].x; v[5] = (__bf16)pf[it][1].y;
      v[6] = (__bf16)pf[it][1].z; v[7] = (__bf16)pf[it][1].w;
      *(bf16x8*)&As[(it * 256 + tid) * 8] = v;
    }
    // stage B: async global->LDS, 16B/lane, chunk-swizzled
    #pragma unroll
    for (int it = 0; it < 4; ++it)
      gl_lds16(Bt + (size_t)sr_[it] * KTOT + k0 + sc_[it] * 8,
               &Bs[(it * 256 + tid) * 8]);
    __syncthreads();

    // issue NEXT K-step's fp32 A loads now; latency hides under the MFMAs
    if (k0 + BK < KTOT) {
      const int kn = k0 + BK;
      const float* base = (kn < DH) ? (Ax + kn) : (Ah + (kn - DH));
      #pragma unroll
      for (int it = 0; it < 4; ++it) {
        const float* s = base + (size_t)sr_[it] * DH + sc_[it] * 8;
        pf[it][0] = *(const float4*)s;
        pf[it][1] = *(const float4*)(s + 4);
      }
    }

    #pragma unroll
    for (int ks = 0; ks < 2; ++ks) {
      const int q = lane >> 4;
      bf16x8 af[4], bfr[4];
      #pragma unroll
      for (int cm = 0; cm < 4; ++cm) {
        int row = wm * 64 + cm * 16 + (lane & 15);
        int cc = (ks * 4 + q) ^ (row & 7);
        af[cm] = *(const bf16x8*)&As[row * BK + cc * 8];
      }
      #pragma unroll
      for (int cn = 0; cn < 4; ++cn) {
        int row = wn * 64 + cn * 16 + (lane & 15);
        int cc = (ks * 4 + q) ^ (row & 7);
        bfr[cn] = *(const bf16x8*)&Bs[row * BK + cc * 8];
      }
      #pragma unroll
      for (int cm = 0; cm < 4; ++cm)
        #pragma unroll
        for (int cn = 0; cn < 4; ++cn)
          acc[cm][cn] = __builtin_amdgcn_mfma_f32_16x16x32_bf16(
              af[cm], bfr[cn], acc[cm][cn], 0, 0, 0);
    }
    __syncthreads();
  }

  // fused LSTM epilogue (NT stores: out never re-read; keep L3 for x/h)
  #pragma unroll
  for (int cm = 0; cm < 4; ++cm) {
    const int rbase = row0 + wm * 64 + cm * 16 + (lane >> 4) * 4;
    #pragma unroll
    for (int i2 = 0; i2 < 4; ++i2) {
      const size_t r = (size_t)(rbase + i2);
      float ig = sigf(acc[cm][0][i2] + bias[0]);
      float fg = sigf(acc[cm][1][i2] + bias[1]);
      float og = sigf(acc[cm][2][i2] + bias[2]);
      float gg = tanhf_(acc[cm][3][i2] + bias[3]);
      float cnew = fg * cpv[cm][i2] + ig * gg;
      float hnew = og * tanhf_(cnew);
      __builtin_nontemporal_store(cnew, &out[r * DH + hd]);
      __builtin_nontemporal_store(hnew, &out[(size_t)BROWS * DH + r * DH + hd]);
    }
  }
}

__global__ void lstm_naive(const float* __restrict__ x, const float* __restrict__ Cin,
                           const float* __restrict__ h, const float* __restrict__ Wx,
                           const float* __restrict__ bxp, const float* __restrict__ Wh,
                           const float* __restrict__ bhp, float* __restrict__ out) {
  int idx = blockIdx.x * 256 + threadIdx.x;
  int r = idx >> 9, hd = idx & 511;
  float z[4];
  #pragma unroll
  for (int g = 0; g < 4; ++g) z[g] = bxp[g * DH + hd] + bhp[g * DH + hd];
  for (int k = 0; k < DH; ++k) {
    float xv = x[(size_t)r * DH + k];
    #pragma unroll
    for (int g = 0; g < 4; ++g) z[g] += xv * Wx[k * 4 * DH + g * DH + hd];
  }
  for (int k = 0; k < DH; ++k) {
    float hv = h[(size_t)r * DH + k];
    #pragma unroll
    for (int g = 0; g < 4; ++g) z[g] += hv * Wh[k * 4 * DH + g * DH + hd];
  }
  float ig = sigf(z[0]), fg = sigf(z[1]), og = sigf(z[2]), gg = tanhf_(z[3]);
  float cp = Cin[(size_t)r * DH + hd];
  float cnew = fg * cp + ig * gg;
  float hnew = og * tanhf_(cnew);
  out[(size_t)r * DH + hd] = cnew;
  out[(size_t)BROWS * DH + (size_t)r * DH + hd] = hnew;
}

extern "C" void kernel_launch(void* const* d_in, const int* in_sizes, int n_in,
                              void* d_out, int out_size, void* d_ws, size_t ws_size,
                              hipStream_t stream) {
  const float* x  = (const float*)d_in[0];
  const float* Ci = (const float*)d_in[1];
  const float* h  = (const float*)d_in[2];
  const float* Wx = (const float*)d_in[3];
  const float* bx = (const float*)d_in[4];
  const float* Wh = (const float*)d_in[5];
  const float* bh = (const float*)d_in[6];
  float* out = (float*)d_out;

  const size_t wt_bytes = (size_t)2048 * KTOT * sizeof(__bf16);          // 4 MB

  if (ws_size >= wt_bytes) {
    __bf16* Wt = (__bf16*)d_ws;
    pack_w<<<dim3(16, 16), dim3(256), 0, stream>>>(Wx, Wh, Wt);
    lstm_fused<<<dim3(16, BROWS / BM), dim3(256), 0, stream>>>(
        x, h, Wt, bx, bh, Ci, out);
  } else {
    lstm_naive<<<dim3((BROWS * DH) / 256), dim3(256), 0, stream>>>(
        x, Ci, h, Wx, bx, Wh, bh, out);
  }
}

// Round 5
// 428.393 us; speedup vs baseline: 1.2559x; 1.2559x over previous
//
#include <hip/hip_runtime.h>
#include <stdint.h>

// LSTM cell, fp32 I/O: z = x@Wx + h@Wh + bx + bh (M=32768, N=2048, K=1024)
// fused with gate activations and C/h update. bf16 MFMA, fp32 accumulate.
// R9: occupancy round. R0 config was best (196us GEMM); diagnosis: latency-
//     bound (Mfma 31 / VALU 39 / HBM 20 / Occ 31.5%). 84 VGPR + 64 AGPR =
//     148/wave -> 3 blocks/CU. Edits:
//     (a) drop cpv[4][4] C-prefetch (-16 VGPR; C loads -> epilogue),
//     (b) __launch_bounds__(256,4) -> <=128 regs -> 4 blocks/CU (16 waves),
//     (c) conv_xh: grid-stride 2048 blocks, 64B/lane reads, NORMAL stores
//         (NT would evict xh from L2/L3 that the GEMM is about to read).
//     Reverted (measured regressions): XCD remap (+13us), NT epilogue, fused-A.

#define BROWS 32768
#define DH 512
#define KTOT 1024   // D_IN + D_H
#define BM 128
#define BK 64

typedef __attribute__((ext_vector_type(8))) __bf16 bf16x8;
typedef __attribute__((ext_vector_type(4))) float f32x4;
typedef __attribute__((address_space(1))) void gvoid;
typedef __attribute__((address_space(3))) void lvoid;

__device__ __forceinline__ void gl_lds16(const void* g, void* l) {
  __builtin_amdgcn_global_load_lds((gvoid*)g, (lvoid*)l, 16, 0, 0);
}

__device__ __forceinline__ float sigf(float v)  { return 1.0f / (1.0f + __expf(-v)); }
__device__ __forceinline__ float tanhf_(float v){ return 1.0f - 2.0f / (1.0f + __expf(2.0f * v)); }

// ---- pre-pass: xh[r][c] = bf16(c<512 ? x[r][c] : h[r][c-512]).
//      Grid-stride, 2048 blocks. Thread owns 16 elems: 64B contiguous read
//      (each half-wave = 2KB run from x or h), 32B contiguous write. ----
#define CONV_BLOCKS 2048
__global__ __launch_bounds__(256) void conv_xh(
    const float* __restrict__ x, const float* __restrict__ h,
    __bf16* __restrict__ xh) {
  const int t = threadIdx.x;
  const int64_t total  = (int64_t)BROWS * (KTOT / 16);          // 16-elem chunks
  const int64_t stride = (int64_t)CONV_BLOCKS * 256;
  for (int64_t i = (int64_t)blockIdx.x * 256 + t; i < total; i += stride) {
    const int64_t r = i >> 6;                   // 64 chunks/row
    const int c = (int)(i & 63) * 16;
    const float* src = (c < DH) ? (x + r * DH + c)
                                : (h + r * DH + (c - DH));
    float4 f0 = *(const float4*)(src + 0);
    float4 f1 = *(const float4*)(src + 4);
    float4 f2 = *(const float4*)(src + 8);
    float4 f3 = *(const float4*)(src + 12);
    bf16x8 v0, v1;
    v0[0] = (__bf16)f0.x; v0[1] = (__bf16)f0.y; v0[2] = (__bf16)f0.z; v0[3] = (__bf16)f0.w;
    v0[4] = (__bf16)f1.x; v0[5] = (__bf16)f1.y; v0[6] = (__bf16)f1.z; v0[7] = (__bf16)f1.w;
    v1[0] = (__bf16)f2.x; v1[1] = (__bf16)f2.y; v1[2] = (__bf16)f2.z; v1[3] = (__bf16)f2.w;
    v1[4] = (__bf16)f3.x; v1[5] = (__bf16)f3.y; v1[6] = (__bf16)f3.z; v1[7] = (__bf16)f3.w;
    bf16x8* dst = (bf16x8*)(xh + r * KTOT + c);
    dst[0] = v0;
    dst[1] = v1;
  }
}

// ---- pack: Wt[(jb*128+r)*1024+k], r = (hl>>4)*64 + g*16 + (hl&15),
//      n = g*512 + jb*32 + hl. Coalesced via LDS transpose tile. ----
__global__ void pack_w(const float* __restrict__ Wx, const float* __restrict__ Wh,
                       __bf16* __restrict__ Wt) {
  __shared__ __bf16 T[128][72];                 // +8 pad
  const int jb = blockIdx.y;
  const int k0 = blockIdx.x * 64;
  const float* Wsrc = (k0 < DH) ? (Wx + (size_t)k0 * 4 * DH)
                                : (Wh + (size_t)(k0 - DH) * 4 * DH);
  const int t = threadIdx.x;
  const int s = t & 31, kr0 = t >> 5;           // 32 seg-threads x 8 k-rows
  const int g = s >> 3, q = s & 7;
  const int r0 = (q >> 2) * 64 + g * 16 + (q & 3) * 4;
  #pragma unroll
  for (int it = 0; it < 8; ++it) {
    int kr = it * 8 + kr0;
    float4 f = *(const float4*)(Wsrc + (size_t)kr * 4 * DH + g * DH + jb * 32 + q * 4);
    T[r0 + 0][kr] = (__bf16)f.x;
    T[r0 + 1][kr] = (__bf16)f.y;
    T[r0 + 2][kr] = (__bf16)f.z;
    T[r0 + 3][kr] = (__bf16)f.w;
  }
  __syncthreads();
  #pragma unroll
  for (int it = 0; it < 4; ++it) {
    int lin = it * 256 + t;                     // 0..1023
    int r = lin >> 3, k8 = lin & 7;
    bf16x8 v;
    #pragma unroll
    for (int j = 0; j < 8; ++j) v[j] = T[r][k8 * 8 + j];
    *(bf16x8*)(Wt + (size_t)(jb * 128 + r) * KTOT + k0 + k8 * 8) = v;
  }
}

// ---- main fused GEMM, m97 structure + XOR swizzle; 4 blocks/CU target ----
__global__ __launch_bounds__(256, 4) void lstm_gemm2(
    const __bf16* __restrict__ xh, const __bf16* __restrict__ Wt,
    const float* __restrict__ bx, const float* __restrict__ bh,
    const float* __restrict__ Cin, float* __restrict__ out) {
  __shared__ __attribute__((aligned(16))) __bf16 As[BM * BK];
  __shared__ __attribute__((aligned(16))) __bf16 Bs[BM * BK];

  const int tid  = threadIdx.x;
  const int lane = tid & 63;
  const int wave = tid >> 6;
  const int wm = wave >> 1, wn = wave & 1;
  const int jb   = blockIdx.x;
  const int row0 = blockIdx.y * BM;

  const __bf16* Bt = Wt + (size_t)jb * 128 * KTOT;

  // bias prefetch (4 VGPR; C loads deferred to epilogue to cut pressure)
  const int hd = jb * 32 + wn * 16 + (lane & 15);
  float bias[4];
  #pragma unroll
  for (int g = 0; g < 4; ++g) bias[g] = bx[g * DH + hd] + bh[g * DH + hd];

  f32x4 acc[4][4];
  #pragma unroll
  for (int a_ = 0; a_ < 4; ++a_)
    #pragma unroll
    for (int b_ = 0; b_ < 4; ++b_) acc[a_][b_] = (f32x4)0.0f;

  for (int k0 = 0; k0 < KTOT; k0 += BK) {
    // stage A,B via async global->LDS, 16B/lane; chunk index XOR-swizzled by
    // (row&7) so fragment ds_read_b128 spreads over all 32 banks.
    #pragma unroll
    for (int it = 0; it < 4; ++it) {
      int lin2 = it * 256 + tid;
      int r = lin2 >> 3, c8 = lin2 & 7;
      int cs = c8 ^ (r & 7);
      gl_lds16(xh + (size_t)(row0 + r) * KTOT + k0 + cs * 8, &As[lin2 * 8]);
    }
    #pragma unroll
    for (int it = 0; it < 4; ++it) {
      int lin2 = it * 256 + tid;
      int r = lin2 >> 3, c8 = lin2 & 7;
      int cs = c8 ^ (r & 7);
      gl_lds16(Bt + (size_t)r * KTOT + k0 + cs * 8, &Bs[lin2 * 8]);
    }
    __syncthreads();

    #pragma unroll
    for (int ks = 0; ks < 2; ++ks) {
      const int q = lane >> 4;
      bf16x8 af[4], bfr[4];
      #pragma unroll
      for (int cm = 0; cm < 4; ++cm) {
        int row = wm * 64 + cm * 16 + (lane & 15);
        int cc = (ks * 4 + q) ^ (row & 7);
        af[cm] = *(const bf16x8*)&As[row * BK + cc * 8];
      }
      #pragma unroll
      for (int cn = 0; cn < 4; ++cn) {
        int row = wn * 64 + cn * 16 + (lane & 15);
        int cc = (ks * 4 + q) ^ (row & 7);
        bfr[cn] = *(const bf16x8*)&Bs[row * BK + cc * 8];
      }
      #pragma unroll
      for (int cm = 0; cm < 4; ++cm)
        #pragma unroll
        for (int cn = 0; cn < 4; ++cn)
          acc[cm][cn] = __builtin_amdgcn_mfma_f32_16x16x32_bf16(
              af[cm], bfr[cn], acc[cm][cn], 0, 0, 0);
    }
    __syncthreads();
  }

  // fused LSTM epilogue (C loaded here; short live ranges)
  #pragma unroll
  for (int cm = 0; cm < 4; ++cm) {
    const int rbase = row0 + wm * 64 + cm * 16 + (lane >> 4) * 4;
    #pragma unroll
    for (int i2 = 0; i2 < 4; ++i2) {
      const size_t r = (size_t)(rbase + i2);
      float cp = Cin[r * DH + hd];
      float ig = sigf(acc[cm][0][i2] + bias[0]);
      float fg = sigf(acc[cm][1][i2] + bias[1]);
      float og = sigf(acc[cm][2][i2] + bias[2]);
      float gg = tanhf_(acc[cm][3][i2] + bias[3]);
      float cnew = fg * cp + ig * gg;
      float hnew = og * tanhf_(cnew);
      out[r * DH + hd] = cnew;
      out[(size_t)BROWS * DH + r * DH + hd] = hnew;
    }
  }
}

// ---- R3 fallback GEMM (fp32 A staging, proven) for 4MB <= ws < 68MB ----
__global__ __launch_bounds__(256, 3) void lstm_gemm(
    const float* __restrict__ x, const float* __restrict__ h,
    const __bf16* __restrict__ Wt, const float* __restrict__ bx,
    const float* __restrict__ bh, const float* __restrict__ Cin,
    float* __restrict__ out) {
  __shared__ __attribute__((aligned(16))) __bf16 Asf[BM * BK];
  __shared__ __attribute__((aligned(16))) __bf16 Bsf[BM * BK];
  const int tid  = threadIdx.x;
  const int lane = tid & 63;
  const int wave = tid >> 6;
  const int wm = wave >> 1, wn = wave & 1;
  const int jb   = blockIdx.x;
  const int row0 = blockIdx.y * BM;
  const __bf16* Bt = Wt + (size_t)jb * 128 * KTOT;
  f32x4 acc[4][4];
  #pragma unroll
  for (int a_ = 0; a_ < 4; ++a_)
    #pragma unroll
    for (int b_ = 0; b_ < 4; ++b_) acc[a_][b_] = (f32x4)0.0f;
  for (int k0 = 0; k0 < KTOT; k0 += BK) {
    const float* Aptr = (k0 < DH) ? (x + (size_t)row0 * DH + k0)
                                  : (h + (size_t)row0 * DH + (k0 - DH));
    bf16x8 ta[4], tb[4];
    #pragma unroll
    for (int it = 0; it < 4; ++it) {
      int lin = it * 256 + tid;
      int r = lin >> 3, c8 = lin & 7;
      const float* src = Aptr + r * DH + c8 * 8;
      float4 f0 = *(const float4*)src;
      float4 f1 = *(const float4*)(src + 4);
      bf16x8 v;
      v[0] = (__bf16)f0.x; v[1] = (__bf16)f0.y; v[2] = (__bf16)f0.z; v[3] = (__bf16)f0.w;
      v[4] = (__bf16)f1.x; v[5] = (__bf16)f1.y; v[6] = (__bf16)f1.z; v[7] = (__bf16)f1.w;
      ta[it] = v;
      tb[it] = *(const bf16x8*)(Bt + (size_t)r * KTOT + k0 + c8 * 8);
    }
    #pragma unroll
    for (int it = 0; it < 4; ++it) {
      int lin = it * 256 + tid;
      *(bf16x8*)&Asf[lin * 8] = ta[it];
      *(bf16x8*)&Bsf[lin * 8] = tb[it];
    }
    __syncthreads();
    #pragma unroll
    for (int ks = 0; ks < 2; ++ks) {
      const int ko = ks * 32 + (lane >> 4) * 8;
      bf16x8 af[4], bfr[4];
      #pragma unroll
      for (int cm = 0; cm < 4; ++cm)
        af[cm] = *(const bf16x8*)&Asf[(wm * 64 + cm * 16 + (lane & 15)) * BK + ko];
      #pragma unroll
      for (int cn = 0; cn < 4; ++cn)
        bfr[cn] = *(const bf16x8*)&Bsf[(wn * 64 + cn * 16 + (lane & 15)) * BK + ko];
      #pragma unroll
      for (int cm = 0; cm < 4; ++cm)
        #pragma unroll
        for (int cn = 0; cn < 4; ++cn)
          acc[cm][cn] = __builtin_amdgcn_mfma_f32_16x16x32_bf16(
              af[cm], bfr[cn], acc[cm][cn], 0, 0, 0);
    }
    __syncthreads();
  }
  const int hd = jb * 32 + wn * 16 + (lane & 15);
  float bias[4];
  #pragma unroll
  for (int g2 = 0; g2 < 4; ++g2) bias[g2] = bx[g2 * DH + hd] + bh[g2 * DH + hd];
  #pragma unroll
  for (int cm = 0; cm < 4; ++cm) {
    const int rbase = row0 + wm * 64 + cm * 16 + (lane >> 4) * 4;
    #pragma unroll
    for (int i2 = 0; i2 < 4; ++i2) {
      const size_t r = (size_t)(rbase + i2);
      float ig = sigf(acc[cm][0][i2] + bias[0]);
      float fg = sigf(acc[cm][1][i2] + bias[1]);
      float og = sigf(acc[cm][2][i2] + bias[2]);
      float gg = tanhf_(acc[cm][3][i2] + bias[3]);
      float cp = Cin[r * DH + hd];
      float cnew = fg * cp + ig * gg;
      float hnew = og * tanhf_(cnew);
      out[r * DH + hd] = cnew;
      out[(size_t)BROWS * DH + r * DH + hd] = hnew;
    }
  }
}

__global__ void lstm_naive(const float* __restrict__ x, const float* __restrict__ Cin,
                           const float* __restrict__ h, const float* __restrict__ Wx,
                           const float* __restrict__ bxp, const float* __restrict__ Wh,
                           const float* __restrict__ bhp, float* __restrict__ out) {
  int idx = blockIdx.x * 256 + threadIdx.x;
  int r = idx >> 9, hd = idx & 511;
  float z[4];
  #pragma unroll
  for (int g = 0; g < 4; ++g) z[g] = bxp[g * DH + hd] + bhp[g * DH + hd];
  for (int k = 0; k < DH; ++k) {
    float xv = x[(size_t)r * DH + k];
    #pragma unroll
    for (int g = 0; g < 4; ++g) z[g] += xv * Wx[k * 4 * DH + g * DH + hd];
  }
  for (int k = 0; k < DH; ++k) {
    float hv = h[(size_t)r * DH + k];
    #pragma unroll
    for (int g = 0; g < 4; ++g) z[g] += hv * Wh[k * 4 * DH + g * DH + hd];
  }
  float ig = sigf(z[0]), fg = sigf(z[1]), og = sigf(z[2]), gg = tanhf_(z[3]);
  float cp = Cin[(size_t)r * DH + hd];
  float cnew = fg * cp + ig * gg;
  float hnew = og * tanhf_(cnew);
  out[(size_t)r * DH + hd] = cnew;
  out[(size_t)BROWS * DH + (size_t)r * DH + hd] = hnew;
}

extern "C" void kernel_launch(void* const* d_in, const int* in_sizes, int n_in,
                              void* d_out, int out_size, void* d_ws, size_t ws_size,
                              hipStream_t stream) {
  const float* x  = (const float*)d_in[0];
  const float* Ci = (const float*)d_in[1];
  const float* h  = (const float*)d_in[2];
  const float* Wx = (const float*)d_in[3];
  const float* bx = (const float*)d_in[4];
  const float* Wh = (const float*)d_in[5];
  const float* bh = (const float*)d_in[6];
  float* out = (float*)d_out;

  const size_t wt_bytes = (size_t)2048 * KTOT * sizeof(__bf16);          // 4 MB
  const size_t xh_bytes = (size_t)BROWS * KTOT * sizeof(__bf16);         // 64 MB

  if (ws_size >= wt_bytes + xh_bytes) {
    __bf16* Wt = (__bf16*)d_ws;
    __bf16* xh = (__bf16*)((char*)d_ws + wt_bytes);
    pack_w<<<dim3(16, 16), dim3(256), 0, stream>>>(Wx, Wh, Wt);
    conv_xh<<<dim3(CONV_BLOCKS), dim3(256), 0, stream>>>(x, h, xh);
    lstm_gemm2<<<dim3(16, BROWS / BM), dim3(256), 0, stream>>>(xh, Wt, bx, bh, Ci, out);
  } else if (ws_size >= wt_bytes) {
    __bf16* Wt = (__bf16*)d_ws;
    pack_w<<<dim3(16, 16), dim3(256), 0, stream>>>(Wx, Wh, Wt);
    lstm_gemm<<<dim3(16, BROWS / BM), dim3(256), 0, stream>>>(x, h, Wt, bx, bh, Ci, out);
  } else {
    lstm_naive<<<dim3((BROWS * DH) / 256), dim3(256), 0, stream>>>(
        x, Ci, h, Wx, bx, Wh, bh, out);
  }
}